// Round 1
// baseline (2906.012 us; speedup 1.0000x reference)
//
#include <hip/hip_runtime.h>
#include <math.h>

#define NAT 100000
#define MNB 12
#define FEA 64
#define NBRF 41
#define C2 128
#define HIDD 768
#define NCONV 3
#define BB 32
#define LL 512
#define EPSV 1e-5f
#define NB_BLK (NAT / 8)   // stats blocks (8 atoms per block)

__device__ __forceinline__ float softplus_f(float x) {
    if (x > 20.f) return x;
    return log1pf(__expf(x));
}
__device__ __forceinline__ float sigmoid_f(float x) {
    return 1.f / (1.f + __expf(-x));
}

// ---------------------------------------------------------------- embed
__global__ __launch_bounds__(256) void k_embed(const int* __restrict__ anum,
                                               const float* __restrict__ emb,
                                               float* __restrict__ af) {
    int idx = blockIdx.x * 256 + threadIdx.x;
    if (idx >= NAT * FEA) return;
    int n = idx >> 6, c = idx & 63;
    af[idx] = emb[anum[n] * FEA + c];
}

// ------------------------------------------- S = af@W[0:64]+b, T = af@W[64:128]
__global__ __launch_bounds__(256) void k_st(const float* __restrict__ af,
                                            const float* __restrict__ Wb,
                                            const float* __restrict__ bb,
                                            float* __restrict__ S,
                                            float* __restrict__ T) {
    __shared__ float Ws[64][128];
    __shared__ float As[16][65];
    int tid = threadIdx.x;
    int a0 = blockIdx.x * 16;
    for (int t = tid; t < 16 * 64; t += 256) {
        int a = t >> 6, k = t & 63;
        As[a][k] = af[(size_t)(a0 + a) * FEA + k];
    }
    int a = tid >> 4, c0 = tid & 15;
    int n = a0 + a;
    for (int half = 0; half < 2; ++half) {
        __syncthreads();
        for (int t = tid; t < 64 * 128; t += 256) {
            int k = t >> 7, c = t & 127;
            Ws[k][c] = Wb[(size_t)(half * 64 + k) * C2 + c];
        }
        __syncthreads();
        float acc[8];
        #pragma unroll
        for (int j = 0; j < 8; ++j) acc[j] = 0.f;
        for (int k = 0; k < 64; ++k) {
            float av = As[a][k];
            #pragma unroll
            for (int j = 0; j < 8; ++j)
                acc[j] = fmaf(av, Ws[k][c0 + j * 16], acc[j]);
        }
        if (half == 0) {
            #pragma unroll
            for (int j = 0; j < 8; ++j) {
                int c = c0 + j * 16;
                S[(size_t)n * C2 + c] = acc[j] + bb[c];
            }
        } else {
            #pragma unroll
            for (int j = 0; j < 8; ++j)
                T[(size_t)n * C2 + c0 + j * 16] = acc[j];
        }
    }
}

// ------------------------------------------- stats pass: per-channel sum/sumsq of gated
__global__ __launch_bounds__(256) void k_stats(const float* __restrict__ S,
                                               const float* __restrict__ T,
                                               const float* __restrict__ nf,
                                               const int* __restrict__ nidx,
                                               const float* __restrict__ Wb,
                                               float* __restrict__ psum,
                                               float* __restrict__ psq) {
    __shared__ float Wn[NBRF][C2];
    __shared__ float NF[96 * NBRF];
    __shared__ int NI[96];
    __shared__ float red1[8][C2];
    __shared__ float red2[8][C2];
    int tid = threadIdx.x;
    int a0 = blockIdx.x * 8;
    for (int t = tid; t < NBRF * C2; t += 256) {
        int k = t >> 7, c = t & 127;
        Wn[k][c] = Wb[(size_t)(128 + k) * C2 + c];
    }
    const float* gsrc = nf + (size_t)a0 * MNB * NBRF;
    for (int t = tid; t < 96 * NBRF; t += 256) NF[t] = gsrc[t];
    if (tid < 96) NI[tid] = nidx[a0 * MNB + tid];
    __syncthreads();
    int sg = tid >> 5;
    int l = tid & 31;
    int c0 = l * 2;
    float acc[12][4];
    #pragma unroll
    for (int s = 0; s < 12; ++s)
        #pragma unroll
        for (int q = 0; q < 4; ++q) acc[s][q] = 0.f;
    for (int k = 0; k < NBRF; ++k) {
        float2 w0 = *(const float2*)&Wn[k][c0];
        float2 w1 = *(const float2*)&Wn[k][64 + c0];
        #pragma unroll
        for (int s = 0; s < 12; ++s) {
            float v = NF[(sg * 12 + s) * NBRF + k];
            acc[s][0] = fmaf(v, w0.x, acc[s][0]);
            acc[s][1] = fmaf(v, w0.y, acc[s][1]);
            acc[s][2] = fmaf(v, w1.x, acc[s][2]);
            acc[s][3] = fmaf(v, w1.y, acc[s][3]);
        }
    }
    int n = a0 + sg;
    float2 s0 = *(const float2*)&S[(size_t)n * C2 + c0];
    float2 s1 = *(const float2*)&S[(size_t)n * C2 + 64 + c0];
    float sm0 = 0, sm1 = 0, sm2 = 0, sm3 = 0;
    float q0 = 0, q1 = 0, q2 = 0, q3 = 0;
    #pragma unroll
    for (int s = 0; s < 12; ++s) {
        int j = NI[sg * 12 + s];
        float2 t0 = *(const float2*)&T[(size_t)j * C2 + c0];
        float2 t1 = *(const float2*)&T[(size_t)j * C2 + 64 + c0];
        float g0 = acc[s][0] + s0.x + t0.x;
        float g1 = acc[s][1] + s0.y + t0.y;
        float g2 = acc[s][2] + s1.x + t1.x;
        float g3 = acc[s][3] + s1.y + t1.y;
        sm0 += g0; q0 += g0 * g0;
        sm1 += g1; q1 += g1 * g1;
        sm2 += g2; q2 += g2 * g2;
        sm3 += g3; q3 += g3 * g3;
    }
    red1[sg][c0] = sm0; red1[sg][c0 + 1] = sm1;
    red1[sg][64 + c0] = sm2; red1[sg][65 + c0] = sm3;
    red2[sg][c0] = q0; red2[sg][c0 + 1] = q1;
    red2[sg][64 + c0] = q2; red2[sg][65 + c0] = q3;
    __syncthreads();
    if (tid < 128) {
        float ts = 0.f, tq = 0.f;
        #pragma unroll
        for (int r = 0; r < 8; ++r) { ts += red1[r][tid]; tq += red2[r][tid]; }
        psum[(size_t)tid * NB_BLK + blockIdx.x] = ts;
        psq[(size_t)tid * NB_BLK + blockIdx.x] = tq;
    }
}

// ------------------------------------------- BN finalize: scale/shift per channel
__global__ __launch_bounds__(256) void k_bnfin(const float* __restrict__ psum,
                                               const float* __restrict__ psq,
                                               const float* __restrict__ g,
                                               const float* __restrict__ b,
                                               float cnt_inv,
                                               float* __restrict__ scale,
                                               float* __restrict__ shift) {
    int c = blockIdx.x;
    int tid = threadIdx.x;
    __shared__ float r1[256], r2[256];
    float s = 0.f, q = 0.f;
    for (int t = tid; t < NB_BLK; t += 256) {
        s += psum[(size_t)c * NB_BLK + t];
        q += psq[(size_t)c * NB_BLK + t];
    }
    r1[tid] = s; r2[tid] = q;
    __syncthreads();
    for (int st = 128; st > 0; st >>= 1) {
        if (tid < st) { r1[tid] += r1[tid + st]; r2[tid] += r2[tid + st]; }
        __syncthreads();
    }
    if (tid == 0) {
        float mean = r1[0] * cnt_inv;
        float var = r2[0] * cnt_inv - mean * mean;
        float sc = g[c] * rsqrtf(var + EPSV);
        scale[c] = sc;
        shift[c] = b[c] - mean * sc;
    }
}

// ------------------------------------------- main pass: BN1 + gate + m-sum + BN2 stats
__global__ __launch_bounds__(256) void k_main(const float* __restrict__ S,
                                              const float* __restrict__ T,
                                              const float* __restrict__ nf,
                                              const int* __restrict__ nidx,
                                              const float* __restrict__ Wb,
                                              const float* __restrict__ sc1,
                                              const float* __restrict__ sh1,
                                              float* __restrict__ summed,
                                              float* __restrict__ psum,
                                              float* __restrict__ psq) {
    __shared__ float Wn[NBRF][C2];
    __shared__ float NF[96 * NBRF];
    __shared__ int NI[96];
    __shared__ float red1[8][FEA];
    __shared__ float red2[8][FEA];
    int tid = threadIdx.x;
    int a0 = blockIdx.x * 8;
    for (int t = tid; t < NBRF * C2; t += 256) {
        int k = t >> 7, c = t & 127;
        Wn[k][c] = Wb[(size_t)(128 + k) * C2 + c];
    }
    const float* gsrc = nf + (size_t)a0 * MNB * NBRF;
    for (int t = tid; t < 96 * NBRF; t += 256) NF[t] = gsrc[t];
    if (tid < 96) NI[tid] = nidx[a0 * MNB + tid];
    __syncthreads();
    int sg = tid >> 5;
    int l = tid & 31;
    int c0 = l * 2;
    float acc[12][4];
    #pragma unroll
    for (int s = 0; s < 12; ++s)
        #pragma unroll
        for (int q = 0; q < 4; ++q) acc[s][q] = 0.f;
    for (int k = 0; k < NBRF; ++k) {
        float2 w0 = *(const float2*)&Wn[k][c0];
        float2 w1 = *(const float2*)&Wn[k][64 + c0];
        #pragma unroll
        for (int s = 0; s < 12; ++s) {
            float v = NF[(sg * 12 + s) * NBRF + k];
            acc[s][0] = fmaf(v, w0.x, acc[s][0]);
            acc[s][1] = fmaf(v, w0.y, acc[s][1]);
            acc[s][2] = fmaf(v, w1.x, acc[s][2]);
            acc[s][3] = fmaf(v, w1.y, acc[s][3]);
        }
    }
    int n = a0 + sg;
    float2 s0 = *(const float2*)&S[(size_t)n * C2 + c0];
    float2 s1 = *(const float2*)&S[(size_t)n * C2 + 64 + c0];
    float a1 = sc1[c0], a2 = sc1[c0 + 1], a3 = sc1[64 + c0], a4 = sc1[65 + c0];
    float h1 = sh1[c0], h2 = sh1[c0 + 1], h3 = sh1[64 + c0], h4 = sh1[65 + c0];
    float ps0 = 0.f, ps1 = 0.f;
    #pragma unroll
    for (int s = 0; s < 12; ++s) {
        int j = NI[sg * 12 + s];
        float2 t0 = *(const float2*)&T[(size_t)j * C2 + c0];
        float2 t1 = *(const float2*)&T[(size_t)j * C2 + 64 + c0];
        float g0 = (acc[s][0] + s0.x + t0.x) * a1 + h1;   // filter c0
        float g1 = (acc[s][1] + s0.y + t0.y) * a2 + h2;   // filter c0+1
        float g2 = (acc[s][2] + s1.x + t1.x) * a3 + h3;   // core c0
        float g3 = (acc[s][3] + s1.y + t1.y) * a4 + h4;   // core c0+1
        ps0 += sigmoid_f(g0) * softplus_f(g2);
        ps1 += sigmoid_f(g1) * softplus_f(g3);
    }
    *(float2*)&summed[(size_t)n * FEA + c0] = make_float2(ps0, ps1);
    red1[sg][c0] = ps0; red1[sg][c0 + 1] = ps1;
    red2[sg][c0] = ps0 * ps0; red2[sg][c0 + 1] = ps1 * ps1;
    __syncthreads();
    if (tid < 64) {
        float ts = 0.f, tq = 0.f;
        #pragma unroll
        for (int r = 0; r < 8; ++r) { ts += red1[r][tid]; tq += red2[r][tid]; }
        psum[(size_t)tid * NB_BLK + blockIdx.x] = ts;
        psq[(size_t)tid * NB_BLK + blockIdx.x] = tq;
    }
}

// ------------------------------------------- residual update
__global__ __launch_bounds__(256) void k_update(float* __restrict__ af,
                                                const float* __restrict__ summed,
                                                const float* __restrict__ sc2,
                                                const float* __restrict__ sh2) {
    int idx = blockIdx.x * 256 + threadIdx.x;
    if (idx >= NAT * FEA) return;
    int c = idx & 63;
    float v = af[idx] + summed[idx] * sc2[c] + sh2[c];
    af[idx] = softplus_f(v);
}

// ------------------------------------------- fc on selected rows + mask
__global__ __launch_bounds__(256) void k_fc(const float* __restrict__ af,
                                            const int* __restrict__ sel,
                                            const float* __restrict__ mask,
                                            const float* __restrict__ W,
                                            const float* __restrict__ bias,
                                            float* __restrict__ out) {
    __shared__ float A[16][64];
    int tid = threadIdx.x;
    int r0 = blockIdx.x * 16;
    for (int t = tid; t < 16 * 64; t += 256) {
        int r = t >> 6, k = t & 63;
        int n = sel[r0 + r];
        A[r][k] = af[(size_t)n * FEA + k];
    }
    __syncthreads();
    float acc[16][3];
    #pragma unroll
    for (int r = 0; r < 16; ++r) { acc[r][0] = 0.f; acc[r][1] = 0.f; acc[r][2] = 0.f; }
    for (int k = 0; k < 64; ++k) {
        float w0 = W[(size_t)k * HIDD + tid];
        float w1 = W[(size_t)k * HIDD + 256 + tid];
        float w2 = W[(size_t)k * HIDD + 512 + tid];
        #pragma unroll
        for (int r = 0; r < 16; ++r) {
            float a = A[r][k];
            acc[r][0] = fmaf(a, w0, acc[r][0]);
            acc[r][1] = fmaf(a, w1, acc[r][1]);
            acc[r][2] = fmaf(a, w2, acc[r][2]);
        }
    }
    float b0 = bias[tid], b1 = bias[256 + tid], b2 = bias[512 + tid];
    #pragma unroll
    for (int r = 0; r < 16; ++r) {
        float mv = mask[r0 + r];
        size_t base = (size_t)(r0 + r) * HIDD;
        out[base + tid] = (acc[r][0] + b0) * mv;
        out[base + 256 + tid] = (acc[r][1] + b1) * mv;
        out[base + 512 + tid] = (acc[r][2] + b2) * mv;
    }
}

__global__ __launch_bounds__(256) void k_mask(const float* __restrict__ mask,
                                              float* __restrict__ out) {
    int idx = blockIdx.x * 256 + threadIdx.x;
    if (idx < BB * LL) out[(size_t)BB * LL * HIDD + idx] = mask[idx];
}

// ---------------------------------------------------------------- launch
extern "C" void kernel_launch(void* const* d_in, const int* in_sizes, int n_in,
                              void* d_out, int out_size, void* d_ws, size_t ws_size,
                              hipStream_t stream) {
    const int* atom_num  = (const int*)d_in[0];
    const int* nbr_idx   = (const int*)d_in[1];
    const float* nbr_fea = (const float*)d_in[2];
    const int* sel_idx   = (const int*)d_in[3];
    const float* mask    = (const float*)d_in[4];
    const float* emb     = (const float*)d_in[5];
    const float* conv_W  = (const float*)d_in[6];
    const float* conv_b  = (const float*)d_in[7];
    const float* bn1_g   = (const float*)d_in[8];
    const float* bn1_b   = (const float*)d_in[9];
    const float* bn2_g   = (const float*)d_in[10];
    const float* bn2_b   = (const float*)d_in[11];
    const float* fc_W    = (const float*)d_in[12];
    const float* fc_b    = (const float*)d_in[13];
    float* out = (float*)d_out;

    float* ws = (float*)d_ws;
    float* af     = ws;                               // N*64
    float* S      = af + (size_t)NAT * FEA;           // N*128
    float* T      = S + (size_t)NAT * C2;             // N*128
    float* summed = T + (size_t)NAT * C2;             // N*64
    float* psum   = summed + (size_t)NAT * FEA;       // 128*NB_BLK
    float* psq    = psum + (size_t)C2 * NB_BLK;       // 128*NB_BLK
    float* sc1    = psq + (size_t)C2 * NB_BLK;        // 128
    float* sh1    = sc1 + C2;                         // 128
    float* sc2    = sh1 + C2;                         // 64
    float* sh2    = sc2 + FEA;                        // 64

    k_embed<<<(NAT * FEA + 255) / 256, 256, 0, stream>>>(atom_num, emb, af);

    for (int i = 0; i < NCONV; ++i) {
        const float* Wb = conv_W + (size_t)i * 169 * C2;
        k_st<<<NAT / 16, 256, 0, stream>>>(af, Wb, conv_b + i * C2, S, T);
        k_stats<<<NAT / 8, 256, 0, stream>>>(S, T, nbr_fea, nbr_idx, Wb, psum, psq);
        k_bnfin<<<C2, 256, 0, stream>>>(psum, psq, bn1_g + i * C2, bn1_b + i * C2,
                                        1.f / (float)(NAT * (long)MNB), sc1, sh1);
        k_main<<<NAT / 8, 256, 0, stream>>>(S, T, nbr_fea, nbr_idx, Wb, sc1, sh1,
                                            summed, psum, psq);
        k_bnfin<<<FEA, 256, 0, stream>>>(psum, psq, bn2_g + i * FEA, bn2_b + i * FEA,
                                         1.f / (float)NAT, sc2, sh2);
        k_update<<<(NAT * FEA + 255) / 256, 256, 0, stream>>>(af, summed, sc2, sh2);
    }

    k_fc<<<BB * LL / 16, 256, 0, stream>>>(af, sel_idx, mask, fc_W, fc_b, out);
    k_mask<<<(BB * LL + 255) / 256, 256, 0, stream>>>(mask, out);
}